// Round 10
// baseline (186.227 us; speedup 1.0000x reference)
//
#include <hip/hip_runtime.h>
#include <hip/hip_bf16.h>
#include <math.h>

// ComplexProjection: out[b,r,p] = | sum_s complex(xr,xi)[b,r,s] * w[r,s,p] |
// B=32768, R=16, S=128, P=128.
// R10: TLP/decoupling experiment on top of R9 (NT DMA staging, W in regs,
// counted vmcnt). 2-r blocks with 64KB LDS -> TWO independent workgroups
// resident per CU (16 waves/CU vs 8): one group's stage-wait bubbles fill
// with the other group's compute; 2x waves smooth fabric latency tails.
// Null result => per-XCD fabric read-return ceiling (~3.7 TB/s) confirmed.
//   - 512 thr = 8 waves = (rr 0..1) x (quarter-P ph 0..3); nt = 2 N-tiles.
//   - stage: one DMA op = one full 1KB row (64 lanes x 16B), NT (aux=2).
//   - uniform per-wave vmcnt(8): [stage(s) 4 | stores(s-1) 8] -> retire stage.
//   - source chunk swizzle lane^(row&15), undone at ds_read (rule #21).

typedef __attribute__((ext_vector_type(8))) __bf16 bf16x8;
typedef __attribute__((ext_vector_type(4))) float f32x4;

#define RS 2048            // x row stride (floats)
#define RP 2048            // out row stride (floats)
#define STRIP 16
#define NSTRIPS 16

typedef const __attribute__((address_space(1))) void* gas_t;
typedef __attribute__((address_space(3))) void* las_t;

__global__ __launch_bounds__(512, 2) void cproj_kernel(
    const float* __restrict__ x_real,
    const float* __restrict__ x_imag,
    const float* __restrict__ proj,
    float* __restrict__ out)
{
    // [buf][arr(re/im)][row][2r x 64 chunks of 16B]. Physical chunk c holds
    // logical chunk c ^ (row&15) (4-bit involution, applied at DMA source).
    __shared__ __attribute__((aligned(16))) float xb[2][2][STRIP][256];

    const int tid  = threadIdx.x;
    const int bid  = blockIdx.x;
    const int r0   = (bid & 7) * 2;        // r-group base (8 groups of 2)
    const int b_base = (bid >> 3) * 256;   // slab base

    const int lane = tid & 63;
    const int wid  = tid >> 6;             // 0..7
    const int rr   = wid >> 2;             // local r (0..1)
    const int ph   = wid & 3;              // p quarter
    const int p0   = ph * 32;
    const int m    = lane & 15;
    const int g    = lane >> 4;            // k-group / D row group

    // staging role: wave w stages array (w>>2), rows (w&3)*4 .. +3,
    // one DMA op per row (64 lanes x 16B = 1KB row).
    const int st_arr  = wid >> 2;
    const int st_row0 = (wid & 3) * 4;
    const float* xsrc = st_arr ? x_imag : x_real;

#define STAGE(buf_, strip_)                                                   \
    do {                                                                      \
        _Pragma("unroll")                                                     \
        for (int i = 0; i < 4; ++i) {                                         \
            const int row = st_row0 + i;                                      \
            const float* gp = xsrc                                            \
                + (size_t)(b_base + (strip_) * STRIP + row) * RS + r0 * 128   \
                + ((lane ^ (row & 15)) << 2);                                 \
            __builtin_amdgcn_global_load_lds(                                 \
                (gas_t)gp, (las_t)&xb[buf_][st_arr][row][0],                  \
                16, 0, 2 /* CPol NT */);                                      \
        }                                                                     \
    } while (0)

    // ---- prologue: stage strip 0; W into regs; drain once ----
    STAGE(0, 0);

    bf16x8 wf[2][4];  // [nt][kk]: p = p0 + nt*16 + m, k = kk*32 + g*8 + j
    {
        const float* wp = proj + (size_t)(r0 + rr) * (128 * 128) + p0 + m;
        #pragma unroll
        for (int nt = 0; nt < 2; ++nt) {
            #pragma unroll
            for (int kk = 0; kk < 4; ++kk) {
                bf16x8 w;
                #pragma unroll
                for (int j = 0; j < 8; ++j) {
                    w[j] = (__bf16)wp[(size_t)(kk * 32 + g * 8 + j) * 128
                                      + nt * 16];
                }
                wf[nt][kk] = w;
            }
        }
    }
    asm volatile("s_waitcnt vmcnt(0)" ::: "memory");  // stage0 + W complete

#define ITER(s_)                                                              \
    {                                                                         \
        /* per-wave queue at wait: [stage(s_) 4, stores(s_-1) 8] -> 8 */      \
        asm volatile("s_waitcnt vmcnt(8)" ::: "memory");                      \
        __builtin_amdgcn_s_barrier();                                         \
        __builtin_amdgcn_sched_barrier(0);                                    \
        if ((s_) + 1 < NSTRIPS) STAGE(((s_) + 1) & 1, (s_) + 1);              \
        bf16x8 ar[2][4];                                                      \
        _Pragma("unroll")                                                     \
        for (int a = 0; a < 2; ++a) {                                         \
            _Pragma("unroll")                                                 \
            for (int kk = 0; kk < 4; ++kk) {                                  \
                const int base = rr * 32 + kk * 8;                            \
                const int clo  = (base + 2 * g)     ^ (m & 15);               \
                const int chi  = (base + 2 * g + 1) ^ (m & 15);               \
                f32x4 lo = *(const f32x4*)&xb[(s_) & 1][a][m][clo * 4];       \
                f32x4 hi = *(const f32x4*)&xb[(s_) & 1][a][m][chi * 4];       \
                bf16x8 t;                                                     \
                _Pragma("unroll")                                             \
                for (int j = 0; j < 4; ++j) {                                 \
                    t[j]     = (__bf16)lo[j];                                 \
                    t[j + 4] = (__bf16)hi[j];                                 \
                }                                                             \
                ar[a][kk] = t;                                                \
            }                                                                 \
        }                                                                     \
        f32x4 acc[2][2];                                                      \
        acc[0][0] = (f32x4)0.0f; acc[0][1] = (f32x4)0.0f;                     \
        acc[1][0] = (f32x4)0.0f; acc[1][1] = (f32x4)0.0f;                     \
        _Pragma("unroll")                                                     \
        for (int kk = 0; kk < 4; ++kk) {                                      \
            _Pragma("unroll")                                                 \
            for (int nt = 0; nt < 2; ++nt) {                                  \
                acc[nt][0] = __builtin_amdgcn_mfma_f32_16x16x32_bf16(         \
                    ar[0][kk], wf[nt][kk], acc[nt][0], 0, 0, 0);              \
                acc[nt][1] = __builtin_amdgcn_mfma_f32_16x16x32_bf16(         \
                    ar[1][kk], wf[nt][kk], acc[nt][1], 0, 0, 0);              \
            }                                                                 \
        }                                                                     \
        /* D mapping (m89): col = lane&15 -> p, row = g*4+j -> b */           \
        float* po = out + (size_t)(b_base + (s_) * STRIP + g * 4) * RP        \
                    + (r0 + rr) * 128 + p0 + m;                               \
        _Pragma("unroll")                                                     \
        for (int nt = 0; nt < 2; ++nt) {                                      \
            _Pragma("unroll")                                                 \
            for (int j = 0; j < 4; ++j) {                                     \
                float re = acc[nt][0][j];                                     \
                float im = acc[nt][1][j];                                     \
                po[(size_t)j * RP + nt * 16] = sqrtf(re * re + im * im);      \
            }                                                                 \
        }                                                                     \
    }

    ITER(0)
    ITER(1)
    ITER(2)
    ITER(3)
    ITER(4)
    ITER(5)
    ITER(6)
    ITER(7)
    ITER(8)
    ITER(9)
    ITER(10)
    ITER(11)
    ITER(12)
    ITER(13)
    ITER(14)
    ITER(15)
#undef ITER
#undef STAGE
}

extern "C" void kernel_launch(void* const* d_in, const int* in_sizes, int n_in,
                              void* d_out, int out_size, void* d_ws, size_t ws_size,
                              hipStream_t stream) {
    const float* x_real = (const float*)d_in[0];
    const float* x_imag = (const float*)d_in[1];
    const float* proj   = (const float*)d_in[2];
    float* out = (float*)d_out;

    dim3 grid(1024);   // 128 slabs x 8 r-groups; 2 blocks resident per CU
    dim3 block(512);
    cproj_kernel<<<grid, block, 0, stream>>>(x_real, x_imag, proj, out);
}

// Round 11
// 136.129 us; speedup vs baseline: 1.3680x; 1.3680x over previous
//
#include <hip/hip_runtime.h>
#include <hip/hip_bf16.h>
#include <math.h>

// ComplexProjection: out[b,r,p] = | sum_s complex(xr,xi)[b,r,s] * w[r,s,p] |
// B=32768, R=16, S=128, P=128.
// R11 = R9 reverted (the measured optimum, 139us). Final configuration:
//   - 4-r-group blocks (2KB contiguous staged rows), 512 threads, 8 waves.
//   - x staged via global_load_lds DMA with NT cache policy (aux=2): bypassing
//     L2/IF$ allocation lifted the read stream 3.3 -> 3.68 TB/s (R9's +10%).
//   - double-buffered 64KB stages, counted vmcnt(16) (never drained in-loop).
//   - W in registers (one-time L2-hot loads), XOR chunk swizzle at the DMA
//     source undone at ds_read (rule #21) for conflict-light LDS reads.
// Roofline evidence: 512MB irreducible fp32 CU-ingress reads / 3.68 TB/s
// = 139us = measured. Depth (R6), XCD affinity (R7), granularity (R8), and
// TLP (R10) all null/negative -> read-return path is the hardware ceiling.

typedef __attribute__((ext_vector_type(8))) __bf16 bf16x8;
typedef __attribute__((ext_vector_type(4))) float f32x4;

#define RS 2048            // x row stride (floats)
#define RP 2048            // out row stride (floats)
#define STRIP 16
#define NSTRIPS 16

typedef const __attribute__((address_space(1))) void* gas_t;
typedef __attribute__((address_space(3))) void* las_t;

__global__ __launch_bounds__(512, 2) void cproj_kernel(
    const float* __restrict__ x_real,
    const float* __restrict__ x_imag,
    const float* __restrict__ proj,
    float* __restrict__ out)
{
    // [buf][arr(re/im)][row][4r x 128 floats]. Row segment = 128 16B-chunks;
    // physical chunk p holds logical chunk p ^ (row&7) (low-3-bit involution).
    __shared__ __attribute__((aligned(16))) float xb[2][2][STRIP][512];

    const int tid  = threadIdx.x;
    const int bid  = blockIdx.x;
    const int r0   = (bid & 3) * 4;        // r-group base
    const int b_base = (bid >> 2) * 256;   // slab base

    const int lane = tid & 63;
    const int wid  = tid >> 6;             // 0..7
    const int rr   = wid >> 1;             // local r (0..3)
    const int ph   = wid & 1;              // p half
    const int p0   = ph * 64;
    const int m    = lane & 15;
    const int g    = lane >> 4;            // k-group / D row group

    // staging role: waves 0-3 stage x_real rows 4w..4w+3, waves 4-7 x_imag
    const int st_arr  = wid >> 2;
    const int st_row0 = (wid & 3) * 4;
    const float* xsrc = st_arr ? x_imag : x_real;

#define STAGE(buf_, strip_)                                                   \
    do {                                                                      \
        _Pragma("unroll")                                                     \
        for (int i = 0; i < 8; ++i) {                                         \
            const int row  = st_row0 + (i >> 1);                              \
            const int half = i & 1;                                           \
            const float* gp = xsrc                                            \
                + (size_t)(b_base + (strip_) * STRIP + row) * RS + r0 * 128   \
                + (((half * 64 + lane) ^ (row & 7)) << 2);                    \
            __builtin_amdgcn_global_load_lds(                                 \
                (gas_t)gp, (las_t)&xb[buf_][st_arr][row][half * 256],         \
                16, 0, 2 /* CPol NT: stream, don't allocate in L2/IF$ */);    \
        }                                                                     \
    } while (0)

    // ---- prologue: stage strip 0; W into regs; drain once ----
    STAGE(0, 0);

    bf16x8 wf[4][4];  // [nt][kk]: p = p0 + nt*16 + m, k = kk*32 + g*8 + j
    {
        const float* wp = proj + (size_t)(r0 + rr) * (128 * 128) + p0 + m;
        #pragma unroll
        for (int nt = 0; nt < 4; ++nt) {
            #pragma unroll
            for (int kk = 0; kk < 4; ++kk) {
                bf16x8 w;
                #pragma unroll
                for (int j = 0; j < 8; ++j) {
                    w[j] = (__bf16)wp[(size_t)(kk * 32 + g * 8 + j) * 128
                                      + nt * 16];
                }
                wf[nt][kk] = w;
            }
        }
    }
    asm volatile("s_waitcnt vmcnt(0)" ::: "memory");  // stage0 + W complete

#define ITER(s_)                                                              \
    {                                                                         \
        /* queue at wait: [stage(s_) 8, stores(s_-1) 16] -> allow 16 */       \
        asm volatile("s_waitcnt vmcnt(16)" ::: "memory");                     \
        __builtin_amdgcn_s_barrier();                                         \
        __builtin_amdgcn_sched_barrier(0);                                    \
        if ((s_) + 1 < NSTRIPS) STAGE(((s_) + 1) & 1, (s_) + 1);              \
        bf16x8 ar[2][4];                                                      \
        _Pragma("unroll")                                                     \
        for (int a = 0; a < 2; ++a) {                                         \
            _Pragma("unroll")                                                 \
            for (int kk = 0; kk < 4; ++kk) {                                  \
                const int base = rr * 32 + kk * 8;                            \
                const int clo  = base + ((2 * g) ^ (m & 7));                  \
                const int chi  = base + ((2 * g + 1) ^ (m & 7));              \
                f32x4 lo = *(const f32x4*)&xb[(s_) & 1][a][m][clo * 4];       \
                f32x4 hi = *(const f32x4*)&xb[(s_) & 1][a][m][chi * 4];       \
                bf16x8 t;                                                     \
                _Pragma("unroll")                                             \
                for (int j = 0; j < 4; ++j) {                                 \
                    t[j]     = (__bf16)lo[j];                                 \
                    t[j + 4] = (__bf16)hi[j];                                 \
                }                                                             \
                ar[a][kk] = t;                                                \
            }                                                                 \
        }                                                                     \
        f32x4 acc[4][2];                                                      \
        _Pragma("unroll")                                                     \
        for (int nt = 0; nt < 4; ++nt) {                                      \
            acc[nt][0] = (f32x4)0.0f;                                         \
            acc[nt][1] = (f32x4)0.0f;                                         \
        }                                                                     \
        _Pragma("unroll")                                                     \
        for (int kk = 0; kk < 4; ++kk) {                                      \
            _Pragma("unroll")                                                 \
            for (int nt = 0; nt < 4; ++nt) {                                  \
                acc[nt][0] = __builtin_amdgcn_mfma_f32_16x16x32_bf16(         \
                    ar[0][kk], wf[nt][kk], acc[nt][0], 0, 0, 0);              \
                acc[nt][1] = __builtin_amdgcn_mfma_f32_16x16x32_bf16(         \
                    ar[1][kk], wf[nt][kk], acc[nt][1], 0, 0, 0);              \
            }                                                                 \
        }                                                                     \
        /* D mapping (m89): col = lane&15 -> p, row = g*4+j -> b */           \
        float* po = out + (size_t)(b_base + (s_) * STRIP + g * 4) * RP        \
                    + (r0 + rr) * 128 + p0 + m;                               \
        _Pragma("unroll")                                                     \
        for (int nt = 0; nt < 4; ++nt) {                                      \
            _Pragma("unroll")                                                 \
            for (int j = 0; j < 4; ++j) {                                     \
                float re = acc[nt][0][j];                                     \
                float im = acc[nt][1][j];                                     \
                po[(size_t)j * RP + nt * 16] = sqrtf(re * re + im * im);      \
            }                                                                 \
        }                                                                     \
    }

    ITER(0)
    ITER(1)
    ITER(2)
    ITER(3)
    ITER(4)
    ITER(5)
    ITER(6)
    ITER(7)
    ITER(8)
    ITER(9)
    ITER(10)
    ITER(11)
    ITER(12)
    ITER(13)
    ITER(14)
    ITER(15)
#undef ITER
#undef STAGE
}

extern "C" void kernel_launch(void* const* d_in, const int* in_sizes, int n_in,
                              void* d_out, int out_size, void* d_ws, size_t ws_size,
                              hipStream_t stream) {
    const float* x_real = (const float*)d_in[0];
    const float* x_imag = (const float*)d_in[1];
    const float* proj   = (const float*)d_in[2];
    float* out = (float*)d_out;

    dim3 grid(512);    // 128 slabs x 4 r-groups
    dim3 block(512);
    cproj_kernel<<<grid, block, 0, stream>>>(x_real, x_imag, proj, out);
}